// Round 3
// baseline (279.966 us; speedup 1.0000x reference)
//
#include <hip/hip_runtime.h>
#include <cstdint>

// Problem constants (reference: B=8, S=2048, D=1024, vocab=50257, p=0.1)
constexpr uint32_t D = 1024;
constexpr uint32_t S = 2048;
constexpr uint32_t TOTAL = 8u * 2048u * 1024u;   // 2^24 elements

// ---------------------------------------------------------------------------
// JAX threefry2x32, key = jax.random.key(42) -> (k1,k2) = (0, 42).
// Partitionable random_bits semantics (current JAX default), bit_width=32:
//   counts_hi, counts_lo = iota_2x32_shape(shape)   (hi = 0 for N < 2^32)
//   bits_1, bits_2 = threefry2x32(key, (counts_hi, counts_lo))
//   bits = bits_1 ^ bits_2            <-- XOR of both outputs
// ---------------------------------------------------------------------------
__device__ __forceinline__ uint32_t rotl32(uint32_t x, int r) {
    return (x << r) | (x >> (32 - r));
}

__device__ __forceinline__ uint32_t threefry_bits_xor(uint32_t ctr) {
    const uint32_t ks0 = 0u;
    const uint32_t ks1 = 42u;
    const uint32_t ks2 = 0x1BD11BDAu ^ 42u;
    uint32_t x0 = ks0;          // counts_hi = 0, + ks0
    uint32_t x1 = ctr + ks1;    // counts_lo = i, + ks1
#define RND(r) x0 += x1; x1 = rotl32(x1, r); x1 ^= x0;
    RND(13) RND(15) RND(26) RND(6)
    x0 += ks1; x1 += ks2 + 1u;
    RND(17) RND(29) RND(16) RND(24)
    x0 += ks2; x1 += ks0 + 2u;
    RND(13) RND(15) RND(26) RND(6)
    x0 += ks0; x1 += ks1 + 3u;
    RND(17) RND(29) RND(16) RND(24)
    x0 += ks1; x1 += ks2 + 4u;
    RND(13) RND(15) RND(26) RND(6)
    x0 += ks2; x1 += ks0 + 5u;
#undef RND
    return x0 ^ x1;   // 32-bit partitionable path XORs the two outputs
}

// uniform = bitcast((bits>>9)|0x3F800000) - 1.0 ; keep iff u < 0.9f
__device__ __forceinline__ float drop_scale(uint32_t bits) {
    float u = __uint_as_float((bits >> 9) | 0x3F800000u) - 1.0f;
    return (u < 0.9f) ? (1.0f / 0.9f) : 0.0f;
}

// One thread handles 4 consecutive flat elements n..n+3 (same b,s; d..d+3).
// A 256-thread block covers exactly one (b,s) row of 1024 elements.
__global__ __launch_bounds__(256) void emb_pe_drop_kernel(
    const int* __restrict__ idx,     // [8, 2048] token ids
    const float* __restrict__ emb,   // [50257, 1024]
    float* __restrict__ out)         // [8, 2048, 1024]
{
    uint32_t n = (blockIdx.x * 256u + threadIdx.x) * 4u;  // flat base index
    uint32_t d = n & (D - 1u);
    uint32_t s = (n >> 10) & (S - 1u);
    uint32_t b = n >> 21;

    int tok = idx[b * S + s];
    const float4 e = *reinterpret_cast<const float4*>(emb + (size_t)tok * D + d);

    // pe[s, 2i]   = sin(s * 10000^(-2i/1024))
    // pe[s, 2i+1] = cos(s * 10000^(-2i/1024)),  i = d>>1 (d is a multiple of 4)
    const float c = -0.02595256324130751f;   // -log2(10000)/512
    float ii = (float)(d >> 1);
    float inv0 = exp2f(ii * c);
    float inv1 = exp2f((ii + 1.0f) * c);
    float pos = (float)s;
    float sin0, cos0, sin1, cos1;
    sincosf(pos * inv0, &sin0, &cos0);
    sincosf(pos * inv1, &sin1, &cos1);

    uint32_t b0 = threefry_bits_xor(n + 0u);
    uint32_t b1 = threefry_bits_xor(n + 1u);
    uint32_t b2 = threefry_bits_xor(n + 2u);
    uint32_t b3 = threefry_bits_xor(n + 3u);

    float4 r;
    r.x = (e.x + sin0) * drop_scale(b0);
    r.y = (e.y + cos0) * drop_scale(b1);
    r.z = (e.z + sin1) * drop_scale(b2);
    r.w = (e.w + cos1) * drop_scale(b3);
    *reinterpret_cast<float4*>(out + n) = r;
}

extern "C" void kernel_launch(void* const* d_in, const int* in_sizes, int n_in,
                              void* d_out, int out_size, void* d_ws, size_t ws_size,
                              hipStream_t stream) {
    const int* idx = (const int*)d_in[0];        // int32 token ids, 8*2048
    const float* emb = (const float*)d_in[1];    // fp32, 50257*1024
    float* out = (float*)d_out;                  // fp32, 2^24

    const uint32_t threads = 256;
    const uint32_t blocks = TOTAL / 4u / threads;  // 16384
    emb_pe_drop_kernel<<<dim3(blocks), dim3(threads), 0, stream>>>(idx, emb, out);
}

// Round 4
// 272.493 us; speedup vs baseline: 1.0274x; 1.0274x over previous
//
#include <hip/hip_runtime.h>
#include <cstdint>

// Problem constants (reference: B=8, S=2048, D=1024, vocab=50257, p=0.1)
constexpr uint32_t D = 1024;
constexpr uint32_t S = 2048;
constexpr uint32_t TOTAL = 8u * 2048u * 1024u;   // 2^24 elements

// ---------------------------------------------------------------------------
// JAX threefry2x32, key = jax.random.key(42) -> (k1,k2) = (0, 42).
// Partitionable random_bits, bit_width=32 (verified round 3, absmax 0.5):
//   bits[i] = out0 ^ out1 of threefry2x32((0,42), (0, i))
// ---------------------------------------------------------------------------
__device__ __forceinline__ uint32_t rotl32(uint32_t x, int r) {
    return (x << r) | (x >> (32 - r));
}

__device__ __forceinline__ uint32_t threefry_bits_xor(uint32_t ctr) {
    const uint32_t ks0 = 0u;
    const uint32_t ks1 = 42u;
    const uint32_t ks2 = 0x1BD11BDAu ^ 42u;
    uint32_t x0 = ks0;          // counts_hi = 0, + ks0
    uint32_t x1 = ctr + ks1;    // counts_lo = i, + ks1
#define RND(r) x0 += x1; x1 = rotl32(x1, r); x1 ^= x0;
    RND(13) RND(15) RND(26) RND(6)
    x0 += ks1; x1 += ks2 + 1u;
    RND(17) RND(29) RND(16) RND(24)
    x0 += ks2; x1 += ks0 + 2u;
    RND(13) RND(15) RND(26) RND(6)
    x0 += ks0; x1 += ks1 + 3u;
    RND(17) RND(29) RND(16) RND(24)
    x0 += ks1; x1 += ks2 + 4u;
    RND(13) RND(15) RND(26) RND(6)
    x0 += ks2; x1 += ks0 + 5u;
#undef RND
    return x0 ^ x1;
}

// uniform = bitcast((bits>>9)|0x3F800000) - 1.0 ; keep iff u < 0.9f
__device__ __forceinline__ float drop_scale(uint32_t bits) {
    float u = __uint_as_float((bits >> 9) | 0x3F800000u) - 1.0f;
    return (u < 0.9f) ? (1.0f / 0.9f) : 0.0f;
}

// Hardware sin/cos: v_sin_f32/v_cos_f32 take REVOLUTIONS; reduce with floor.
__device__ __forceinline__ void hw_sincos_rev(float rev, float& s, float& c) {
    float f = rev - floorf(rev);                 // v_fract
    s = __builtin_amdgcn_sinf(f);
    c = __builtin_amdgcn_cosf(f);
}

// One thread handles 4 consecutive flat elements n..n+3 (same b,s; d..d+3).
// A 256-thread block covers exactly one (b,s) row of 1024 elements.
__global__ __launch_bounds__(256) void emb_pe_drop_kernel(
    const int* __restrict__ idx,     // [8, 2048] token ids
    const float* __restrict__ emb,   // [50257, 1024]
    float* __restrict__ out)         // [8, 2048, 1024]
{
    uint32_t n = (blockIdx.x * 256u + threadIdx.x) * 4u;  // flat base index
    uint32_t d = n & (D - 1u);
    uint32_t s = (n >> 10) & (S - 1u);
    uint32_t b = n >> 21;

    int tok = idx[b * S + s];
    const float4 e = *reinterpret_cast<const float4*>(emb + (size_t)tok * D + d);

    // pe[s, 2i]   = sin(s * 10000^(-2i/1024)),  pe[s, 2i+1] = cos(...)
    // angle in revolutions: rev = s * exp2(ii*c + K), K = -log2(2*pi)
    const float c = -0.02595256324130751f;       // -log2(10000)/512
    const float K = -2.6514961294723187f;        // -log2(2*pi)
    float ii = (float)(d >> 1);
    float invr0 = __builtin_amdgcn_exp2f(ii * c + K);
    float invr1 = __builtin_amdgcn_exp2f((ii + 1.0f) * c + K);
    float pos = (float)s;
    float sin0, cos0, sin1, cos1;
    hw_sincos_rev(pos * invr0, sin0, cos0);
    hw_sincos_rev(pos * invr1, sin1, cos1);

    uint32_t b0 = threefry_bits_xor(n + 0u);
    uint32_t b1 = threefry_bits_xor(n + 1u);
    uint32_t b2 = threefry_bits_xor(n + 2u);
    uint32_t b3 = threefry_bits_xor(n + 3u);

    float4 r;
    r.x = (e.x + sin0) * drop_scale(b0);
    r.y = (e.y + cos0) * drop_scale(b1);
    r.z = (e.z + sin1) * drop_scale(b2);
    r.w = (e.w + cos1) * drop_scale(b3);
    *reinterpret_cast<float4*>(out + n) = r;
}

extern "C" void kernel_launch(void* const* d_in, const int* in_sizes, int n_in,
                              void* d_out, int out_size, void* d_ws, size_t ws_size,
                              hipStream_t stream) {
    const int* idx = (const int*)d_in[0];        // int32 token ids, 8*2048
    const float* emb = (const float*)d_in[1];    // fp32, 50257*1024
    float* out = (float*)d_out;                  // fp32, 2^24

    const uint32_t threads = 256;
    const uint32_t blocks = TOTAL / 4u / threads;  // 16384
    emb_pe_drop_kernel<<<dim3(blocks), dim3(threads), 0, stream>>>(idx, emb, out);
}